// Round 5
// baseline (1915.704 us; speedup 1.0000x reference)
//
#include <hip/hip_runtime.h>
#include <math.h>

#define N_NODES 65536
#define NPG     4096
#define D_IN    34
#define EMB     34
#define S_DIM   4
#define P_DIM   22
#define CONCAT  78      // EMB + 2*P_DIM
#define WIDTH   126
#define KNN     8
#define HPAD    24      // padded h row (22 -> 24)
#define EPAD    36      // padded emb row (34 -> 36)
#define TILE    1024    // j-tile staged in LDS
#define NSPLIT  16      // lanes per node
#define FBIG    3.4e38f

__device__ __forceinline__ float elu1(float v) {
    return v > 0.f ? v : expm1f(v);
}

__device__ __forceinline__ bool lexlt(float da, int ja, float db, int jb) {
    return (da < db) || (da == db && ja < jb);
}

// branchless insert of (dd,jj) into sorted-desc depth-5 (slot 0 = worst kept)
__device__ __forceinline__ void ins5(float (&d)[5], int (&ix)[5], float dd, int jj) {
    const bool s0 = dd < d[0];            // tie keeps resident (smaller j) - lex ok
    d[0] = s0 ? dd : d[0]; ix[0] = s0 ? jj : ix[0];
#pragma unroll
    for (int r = 0; r < 4; ++r) {
        const bool s = d[r] < d[r + 1];
        const float a = s ? d[r + 1] : d[r], b = s ? d[r] : d[r + 1];
        const int   x = s ? ix[r + 1] : ix[r], y = s ? ix[r] : ix[r + 1];
        d[r] = a; d[r + 1] = b; ix[r] = x; ix[r + 1] = y;
    }
}

// branchless insert into sorted-desc depth-8 (fallback path)
__device__ __forceinline__ void ins8(float (&d)[8], int (&ix)[8], float dd, int jj) {
    const bool s0 = dd < d[0];
    d[0] = s0 ? dd : d[0]; ix[0] = s0 ? jj : ix[0];
#pragma unroll
    for (int r = 0; r < 7; ++r) {
        const bool s = d[r] < d[r + 1];
        const float a = s ? d[r + 1] : d[r], b = s ? d[r] : d[r + 1];
        const int   x = s ? ix[r + 1] : ix[r], y = s ? ix[r] : ix[r + 1];
        d[r] = a; d[r + 1] = b; ix[r] = x; ix[r + 1] = y;
    }
}

// bitonic cleaner: sort a bitonic 8-seq desc by lex (d,j)
__device__ __forceinline__ void clean8(float (&md)[8], int (&mj)[8]) {
#define CASL(i, k) { const bool sw = lexlt(md[i], mj[i], md[k], mj[k]); \
    const float a = sw ? md[k] : md[i], b = sw ? md[i] : md[k]; \
    const int   x = sw ? mj[k] : mj[i], y = sw ? mj[i] : mj[k]; \
    md[i] = a; md[k] = b; mj[i] = x; mj[k] = y; }
    CASL(0,4) CASL(1,5) CASL(2,6) CASL(3,7)
    CASL(0,2) CASL(1,3) CASL(4,6) CASL(5,7)
    CASL(0,1) CASL(2,3) CASL(4,5) CASL(6,7)
#undef CASL
}

// keep 8 lex-smallest of mine(sorted desc) + xor-m partner's, re-sorted desc
__device__ __forceinline__ void merge8(float (&md)[8], int (&mj)[8], int m) {
    float pd[8]; int pj[8];
#pragma unroll
    for (int i = 0; i < 8; ++i) { pd[i] = __shfl_xor(md[i], m); pj[i] = __shfl_xor(mj[i], m); }
#pragma unroll
    for (int i = 0; i < 8; ++i) {
        const bool lt = lexlt(md[i], mj[i], pd[7 - i], pj[7 - i]);
        const float nd = lt ? md[i] : pd[7 - i];
        const int   nj = lt ? mj[i] : pj[7 - i];
        md[i] = nd; mj[i] = nj;
    }
    clean8(md, mj);
}

// ---------------------------------------------------------------------------
// s = emb @ Ws + bs   [N,4];   h = emb @ Wh + bh   [N,22] (stored padded to 24)
// ---------------------------------------------------------------------------
__global__ __launch_bounds__(256) void sh_kernel(
        const float* __restrict__ emb, int eld,
        const float* __restrict__ Ws, const float* __restrict__ bs,
        const float* __restrict__ Wh, const float* __restrict__ bh,
        float* __restrict__ s_out, float* __restrict__ h_out) {
    __shared__ float lWs[EMB * S_DIM];
    __shared__ float lWh[EMB * P_DIM];
    __shared__ float lbs[S_DIM];
    __shared__ float lbh[P_DIM];
    for (int t = threadIdx.x; t < EMB * S_DIM; t += 256) lWs[t] = Ws[t];
    for (int t = threadIdx.x; t < EMB * P_DIM; t += 256) lWh[t] = Wh[t];
    if (threadIdx.x < S_DIM) lbs[threadIdx.x] = bs[threadIdx.x];
    if (threadIdx.x < P_DIM) lbh[threadIdx.x] = bh[threadIdx.x];
    __syncthreads();

    const int n = blockIdx.x * 256 + threadIdx.x;
    const float* __restrict__ row = emb + (size_t)n * eld;
    float e[EMB];
#pragma unroll
    for (int r = 0; r < EMB; ++r) e[r] = row[r];

    float s[S_DIM], h[P_DIM];
#pragma unroll
    for (int c = 0; c < S_DIM; ++c) s[c] = lbs[c];
#pragma unroll
    for (int c = 0; c < P_DIM; ++c) h[c] = lbh[c];
#pragma unroll
    for (int r = 0; r < EMB; ++r) {
        const float er = e[r];
#pragma unroll
        for (int c = 0; c < S_DIM; ++c) s[c] = fmaf(er, lWs[r * S_DIM + c], s[c]);
#pragma unroll
        for (int c = 0; c < P_DIM; ++c) h[c] = fmaf(er, lWh[r * P_DIM + c], h[c]);
    }
    ((float4*)s_out)[n] = make_float4(s[0], s[1], s[2], s[3]);
    float* __restrict__ hr = h_out + (size_t)n * HPAD;
#pragma unroll
    for (int c = 0; c < P_DIM; ++c) hr[c] = h[c];
}

// ---------------------------------------------------------------------------
// per-node finish: exact lex merge of 16 depth-5 lists, soundness flag,
// rare exact fallback, aggregation (1 neighbor/lane, butterfly), fused GEMM.
// ---------------------------------------------------------------------------
template <int ELD, bool TOUT>
__device__ __forceinline__ void node_finish(
        const float (&dL)[5], const int (&iL)[5],
        int ql, int gbase, int nglob, const float4 si,
        const float4* __restrict__ sgf,
        const float* __restrict__ h_buf,
        const float* __restrict__ emb_in,
        const float* __restrict__ wot,
        const float* __restrict__ bol,
        float* __restrict__ out) {
    // ---- xor-1 pair merge of two depth-5 lists -> top-8 of 10 ----
    float md[8]; int mj[8];
    {
        float qd[5]; int qj[5];
#pragma unroll
        for (int i = 0; i < 5; ++i) { qd[i] = __shfl_xor(dL[i], 1); qj[i] = __shfl_xor(iL[i], 1); }
        md[0] = qd[4]; mj[0] = qj[4];
        md[1] = qd[3]; mj[1] = qj[3];
        md[2] = qd[2]; mj[2] = qj[2];
        { const bool lt = lexlt(dL[0], iL[0], qd[1], qj[1]);
          md[3] = lt ? dL[0] : qd[1]; mj[3] = lt ? iL[0] : qj[1]; }
        { const bool lt = lexlt(dL[1], iL[1], qd[0], qj[0]);
          md[4] = lt ? dL[1] : qd[0]; mj[4] = lt ? iL[1] : qj[0]; }
        md[5] = dL[2]; mj[5] = iL[2];
        md[6] = dL[3]; mj[6] = iL[3];
        md[7] = dL[4]; mj[7] = iL[4];
        clean8(md, mj);
    }
    merge8(md, mj, 2);
    merge8(md, mj, 4);
    merge8(md, mj, 8);

    // ---- soundness flag: my 5th-best made the final top-8 => may have lost
    const bool lost = !lexlt(md[0], mj[0], dL[0], iL[0]);
    const unsigned long long bal = __ballot(lost);
    const bool flag = ((bal >> (threadIdx.x & 48)) & 0xFFFFull) != 0ull;
    if (flag) {   // group-uniform: exact rescan of this node (global s, L2-hot)
        float fd[8]; int fj[8];
#pragma unroll
        for (int r = 0; r < 8; ++r) { fd[r] = FBIG; fj[r] = 0; }
        for (int s = 0; s < NPG / NSPLIT; ++s) {
            const int j = NSPLIT * s + ql;
            const float4 sj = sgf[j];
            const float dx = si.x - sj.x, dy = si.y - sj.y;
            const float dz = si.z - sj.z, dw = si.w - sj.w;
            const float d2 = fmaf(dx, dx, fmaf(dy, dy, fmaf(dz, dz, dw * dw)));
            ins8(fd, fj, d2, j);
        }
        merge8(fd, fj, 1);
        merge8(fd, fj, 2);
        merge8(fd, fj, 4);
        merge8(fd, fj, 8);
#pragma unroll
        for (int r = 0; r < 8; ++r) { md[r] = fd[r]; mj[r] = fj[r]; }
    }

    // ---- slot select: lane ql (<8) handles neighbor md[ql] ----
    float ds = md[0]; int js = mj[0];
#pragma unroll
    for (int r = 1; r < 8; ++r) {
        const bool p = (ql == r);
        ds = p ? md[r] : ds; js = p ? mj[r] : js;
    }
    const bool act = ql < 8;

    float sm[P_DIM], mx[P_DIM];
    if (act) {
        const float w = expf(-10.f * ds);
        const float4* __restrict__ hrow =
            (const float4*)(h_buf + (size_t)(gbase + js) * HPAD);
        const float4 q0 = hrow[0], q1 = hrow[1], q2 = hrow[2];
        const float4 q3 = hrow[3], q4 = hrow[4], q5 = hrow[5];
        const float vv[P_DIM] = {q0.x,q0.y,q0.z,q0.w, q1.x,q1.y,q1.z,q1.w,
                                 q2.x,q2.y,q2.z,q2.w, q3.x,q3.y,q3.z,q3.w,
                                 q4.x,q4.y,q4.z,q4.w, q5.x,q5.y};
#pragma unroll
        for (int c = 0; c < P_DIM; ++c) { const float mv = w * vv[c]; sm[c] = mv; mx[c] = mv; }
    } else {
#pragma unroll
        for (int c = 0; c < P_DIM; ++c) { sm[c] = 0.f; mx[c] = -FBIG; }
    }
#pragma unroll
    for (int m = 1; m <= 8; m <<= 1) {
#pragma unroll
        for (int c = 0; c < P_DIM; ++c) {
            sm[c] += __shfl_xor(sm[c], m);
            mx[c] = fmaxf(mx[c], __shfl_xor(mx[c], m));
        }
    }
#pragma unroll
    for (int c = 0; c < P_DIM; ++c) sm[c] *= 0.125f;

    // ---- fused output GEMM: cols c = ql + 16*m ----
    float e[EMB];
    const float* __restrict__ erow = emb_in + (size_t)nglob * ELD;
    if constexpr (ELD == 34) {
#pragma unroll
        for (int i = 0; i < 17; ++i) {
            const float2 v = ((const float2*)erow)[i];
            e[2 * i] = v.x; e[2 * i + 1] = v.y;
        }
    } else {
#pragma unroll
        for (int i = 0; i < 8; ++i) {
            const float4 v = ((const float4*)erow)[i];
            e[4 * i] = v.x; e[4 * i + 1] = v.y; e[4 * i + 2] = v.z; e[4 * i + 3] = v.w;
        }
        const float2 v = ((const float2*)erow)[16];
        e[32] = v.x; e[33] = v.y;
    }
#pragma unroll
    for (int m = 0; m < 3; ++m) {
        const int c = ql + 16 * m;
        if (c < EMB) {
            const float* __restrict__ wr = &wot[c * 81];
            float acc = bol[c];
#pragma unroll
            for (int r = 0; r < EMB; ++r)   acc = fmaf(e[r], wr[r], acc);
#pragma unroll
            for (int p = 0; p < P_DIM; ++p) acc = fmaf(sm[p], wr[34 + p], acc);
#pragma unroll
            for (int p = 0; p < P_DIM; ++p) acc = fmaf(mx[p], wr[56 + p], acc);
            if constexpr (TOUT)
                out[(size_t)c * N_NODES + nglob] = acc;
            else
                out[(size_t)nglob * EPAD + c] = acc;
        }
    }
}

// ---------------------------------------------------------------------------
// GravNet v5: exact single-pass kNN. 16 lanes/node (bins of 256), 2 nodes per
// group, depth-5 branchless lists, exact merge + flag + rare exact fallback.
// grid = 16 graphs * 128 blocks; block = 256 thr = 16 groups x (2 nodes).
// ---------------------------------------------------------------------------
template <int ELD, bool TOUT>
__global__ __launch_bounds__(256, 4) void grav_kernel(
        const float* __restrict__ emb_in,
        const float* __restrict__ s_buf,
        const float* __restrict__ h_buf,
        const float* __restrict__ Wo, const float* __restrict__ bo,
        float* __restrict__ out) {
    __shared__ float4 sl[TILE];           // 16 KB j-tile
    __shared__ float  wot[EMB * 81];      // Wo^T, rows padded 78 -> 81
    __shared__ float  bol[EMB];

    const int g     = blockIdx.x >> 7;    // 128 blocks per graph
    const int chunk = blockIdx.x & 127;   // 32 nodes per block
    const int gbase = g * NPG;
    const int tid   = threadIdx.x;
    const int ql    = tid & 15;           // lane within node-group
    const int grp   = tid >> 4;           // 16 groups per block
    const int nA    = gbase + chunk * 32 + grp * 2;
    const int nB    = nA + 1;

    for (int t = tid; t < CONCAT * EMB; t += 256) {
        const int r = t / EMB, c = t % EMB;
        wot[c * 81 + r] = Wo[t];
    }
    if (tid < EMB) bol[tid] = bo[tid];

    const float4* __restrict__ sg = (const float4*)s_buf + gbase;
    float4 pre[4];
#pragma unroll
    for (int i = 0; i < 4; ++i) pre[i] = sg[tid + 256 * i];
    const float4 siA = ((const float4*)s_buf)[nA];
    const float4 siB = ((const float4*)s_buf)[nB];

    float dA[5], dB[5]; int jA[5], jB[5];
#pragma unroll
    for (int r = 0; r < 5; ++r) { dA[r] = FBIG; jA[r] = 0; dB[r] = FBIG; jB[r] = 0; }

#pragma unroll
    for (int i = 0; i < 4; ++i) sl[tid + 256 * i] = pre[i];
    __syncthreads();

    for (int t = 0; t < NPG / TILE; ++t) {
        if (t < NPG / TILE - 1) {
#pragma unroll
            for (int i = 0; i < 4; ++i)
                pre[i] = sg[(t + 1) * TILE + tid + 256 * i];
        }
        const int jb = t * TILE + ql;
#pragma unroll 4
        for (int k = 0; k < TILE / NSPLIT; ++k) {
            const float4 sj = sl[NSPLIT * k + ql];  // 16 bcast addrs: conflict-free
            const int jj = jb + NSPLIT * k;
            {
                const float dx = siA.x - sj.x, dy = siA.y - sj.y;
                const float dz = siA.z - sj.z, dw = siA.w - sj.w;
                const float d2 = fmaf(dx, dx, fmaf(dy, dy, fmaf(dz, dz, dw * dw)));
                ins5(dA, jA, d2, jj);
            }
            {
                const float dx = siB.x - sj.x, dy = siB.y - sj.y;
                const float dz = siB.z - sj.z, dw = siB.w - sj.w;
                const float d2 = fmaf(dx, dx, fmaf(dy, dy, fmaf(dz, dz, dw * dw)));
                ins5(dB, jB, d2, jj);
            }
        }
        if (t < NPG / TILE - 1) {
            __syncthreads();
#pragma unroll
            for (int i = 0; i < 4; ++i) sl[tid + 256 * i] = pre[i];
            __syncthreads();
        }
    }

    node_finish<ELD, TOUT>(dA, jA, ql, gbase, nA, siA, sg, h_buf, emb_in, wot, bol, out);
    node_finish<ELD, TOUT>(dB, jB, ql, gbase, nB, siB, sg, h_buf, emb_in, wot, bol, out);
}

// ---------------------------------------------------------------------------
// Hidden MLP layer on transposed activations: outT[c][n] = act(inT @ W + b).
// ---------------------------------------------------------------------------
template <int K, bool DOELU>
__global__ __launch_bounds__(256, 4) void mlp_t(
        const float* __restrict__ inT,    // [K][N]
        const float* __restrict__ W,      // [K][126] natural layout
        const float* __restrict__ b,      // [126]
        float* __restrict__ outT) {       // [126][N]
    __shared__ float xs[K * 64];
    const int rowbase = blockIdx.x * 64;
    for (int t = threadIdx.x; t < K * 64; t += 256) {
        const int k = t >> 6, r = t & 63;
        xs[t] = inT[(size_t)k * N_NODES + rowbase + r];
    }
    __syncthreads();

    int colbase = __builtin_amdgcn_readfirstlane(threadIdx.x >> 6) * 32;
    if (colbase > WIDTH - 32) colbase = WIDTH - 32;   // wave 3: cols 94..125
    const int lane = threadIdx.x & 63;
    const int row  = rowbase + lane;

    float acc[32];
#pragma unroll
    for (int o = 0; o < 32; ++o) acc[o] = b[colbase + o];

#pragma unroll 2
    for (int k = 0; k < K; ++k) {
        const float xk = xs[k * 64 + lane];
        const float* __restrict__ wrow = W + (size_t)k * WIDTH + colbase;
#pragma unroll
        for (int o = 0; o < 32; ++o) acc[o] = fmaf(xk, wrow[o], acc[o]);
    }

#pragma unroll
    for (int o = 0; o < 32; ++o) {
        float v = acc[o];
        if (DOELU) v = elu1(v);
        outT[(size_t)(colbase + o) * N_NODES + row] = v;
    }
}

// ---------------------------------------------------------------------------
// Final projection from transposed activations.
// ---------------------------------------------------------------------------
template <int ODIM, bool ADDX>
__global__ __launch_bounds__(256) void final_t(
        const float* __restrict__ actT,   // [126][N]
        const float* __restrict__ Wf,     // [126][ODIM] natural layout
        const float* __restrict__ bf,
        const float* __restrict__ xin,
        float* __restrict__ outp) {
    const int row = blockIdx.x * 256 + threadIdx.x;
    float acc[ODIM];
#pragma unroll
    for (int o = 0; o < ODIM; ++o) acc[o] = bf[o];
#pragma unroll 2
    for (int k = 0; k < WIDTH; ++k) {
        const float a = actT[(size_t)k * N_NODES + row];
#pragma unroll
        for (int o = 0; o < ODIM; ++o) acc[o] = fmaf(a, Wf[k * ODIM + o], acc[o]);
    }
#pragma unroll
    for (int o = 0; o < ODIM; ++o) {
        float v = acc[o];
        if (ADDX) v += xin[(size_t)row * D_IN + 1 + o];
        outp[(size_t)row * ODIM + o] = v;
    }
}

// ---------------------------------------------------------------------------
extern "C" void kernel_launch(void* const* d_in, const int* in_sizes, int n_in,
                              void* d_out, int out_size, void* d_ws, size_t ws_size,
                              hipStream_t stream) {
    (void)in_sizes; (void)n_in; (void)out_size;

    const float* x   = (const float*)d_in[0];
    const float* cWs = (const float*)d_in[1];
    const float* cbs = (const float*)d_in[2];
    const float* cWh = (const float*)d_in[3];
    const float* cbh = (const float*)d_in[4];
    const float* cWo = (const float*)d_in[5];
    const float* cbo = (const float*)d_in[6];
    const float* hW0[3] = {(const float*)d_in[7],  (const float*)d_in[13], (const float*)d_in[19]};
    const float* hb0[3] = {(const float*)d_in[8],  (const float*)d_in[14], (const float*)d_in[20]};
    const float* hWh[3] = {(const float*)d_in[9],  (const float*)d_in[15], (const float*)d_in[21]};
    const float* hbh[3] = {(const float*)d_in[10], (const float*)d_in[16], (const float*)d_in[22]};
    const float* hWf[3] = {(const float*)d_in[11], (const float*)d_in[17], (const float*)d_in[23]};
    const float* hbf[3] = {(const float*)d_in[12], (const float*)d_in[18], (const float*)d_in[24]};
    float* outp = (float*)d_out;
    float* ws = (float*)d_ws;

    // workspace layout (floats)
    const size_t OFF_S   = 0;
    const size_t OFF_H   = OFF_S   + (size_t)N_NODES * 4;
    const size_t OFF_E1  = OFF_H   + (size_t)N_NODES * HPAD;
    const size_t OFF_E2T = OFF_E1  + (size_t)N_NODES * EPAD;
    const size_t OFF_AA  = OFF_E2T + (size_t)EMB * N_NODES;
    const size_t OFF_AB  = OFF_AA  + (size_t)WIDTH * N_NODES;
    const size_t WS_END  = OFF_AB  + (size_t)WIDTH * N_NODES;
    if (ws_size < WS_END * sizeof(float)) return;

    float* s_buf  = ws + OFF_S;
    float* h_buf  = ws + OFF_H;
    float* emb1   = ws + OFF_E1;
    float* emb2T  = ws + OFF_E2T;
    float* act_a  = ws + OFF_AA;
    float* act_b  = ws + OFF_AB;

    // ---- GravNet conv 1 (emb = x, row-major out) ----
    sh_kernel<<<256, 256, 0, stream>>>(x, D_IN, cWs, cbs, cWh, cbh, s_buf, h_buf);
    grav_kernel<34, false><<<2048, 256, 0, stream>>>(x, s_buf, h_buf, cWo, cbo, emb1);
    // ---- GravNet conv 2 (transposed out for heads) ----
    sh_kernel<<<256, 256, 0, stream>>>(emb1, EPAD, cWs + EMB * S_DIM, cbs + S_DIM,
                                       cWh + EMB * P_DIM, cbh + P_DIM, s_buf, h_buf);
    grav_kernel<36, true><<<2048, 256, 0, stream>>>(emb1, s_buf, h_buf,
                                                    cWo + CONCAT * EMB, cbo + EMB, emb2T);

    // ---- heads ----
    const size_t ooff[3] = {0, (size_t)N_NODES * 8, (size_t)N_NODES * 12};
    for (int hd = 0; hd < 3; ++hd) {
        mlp_t<EMB, true><<<1024, 256, 0, stream>>>(emb2T, hW0[hd], hb0[hd], act_a);
        mlp_t<WIDTH, true><<<1024, 256, 0, stream>>>(act_a, hWh[hd], hbh[hd], act_b);
        mlp_t<WIDTH, true><<<1024, 256, 0, stream>>>(act_b, hWh[hd] + WIDTH * WIDTH,
                                                     hbh[hd] + WIDTH, act_a);
        if (hd == 0)
            final_t<8, false><<<256, 256, 0, stream>>>(act_a, hWf[hd], hbf[hd], x, outp + ooff[hd]);
        else if (hd == 1)
            final_t<4, true><<<256, 256, 0, stream>>>(act_a, hWf[hd], hbf[hd], x, outp + ooff[hd]);
        else
            final_t<1, false><<<256, 256, 0, stream>>>(act_a, hWf[hd], hbf[hd], x, outp + ooff[hd]);
    }
}